// Round 1
// baseline (164665.295 us; speedup 1.0000x reference)
//
#include <hip/hip_runtime.h>
#include <hip/hip_bf16.h>

// ---------------------------------------------------------------------------
// Lattice LSTM (bidirectional), MI355X round 0: correctness-first baseline.
//
// Structure:
//   k_embed     : x = E[inputs]; xg = x@W_ih + b (768), xa = x@aW_ih + ab (256)
//                 for both directions (bw uses reversed x).     [parallel]
//   k_wordgates : wg[t][w] = word_table[id]@wW_ih + wb (768), valid slots only,
//                 stored bf16.                                   [parallel]
//   k_scan      : the sequential lattice recurrence, one block per direction.
//                 (h,c) history kept in an 8-deep LDS ring (deps reach <=6 back).
//                 Streams W_hh/wW_hh/aW_hh f32 from L2 each step (known
//                 bottleneck; redesign to resident-weight multi-block later).
//   k_proj      : out[t] = concat(hf[t], hb[T-1-t]) @ W_lin + b_lin.
//
// Workspace (~71.3 MB): xg f32 | xa f32 | hseq f32 | wg bf16
// ---------------------------------------------------------------------------

#define TSEQ 2048
#define KEND 8
#define DEMB 100
#define H    256
#define H3   768
#define WD   300
#define CCLS 18

__device__ __forceinline__ float sigf(float x) { return 1.0f / (1.0f + expf(-x)); }

// ---------------- K1: char embedding -> char-gate / alpha input preacts -----
__global__ __launch_bounds__(256) void k_embed(
    const int* __restrict__ inputs, const float* __restrict__ E,
    const float* __restrict__ W_ih_f, const float* __restrict__ b_f,
    const float* __restrict__ aW_ih_f, const float* __restrict__ ab_f,
    const float* __restrict__ W_ih_b, const float* __restrict__ b_b,
    const float* __restrict__ aW_ih_b, const float* __restrict__ ab_b,
    float* __restrict__ xg, float* __restrict__ xa)
{
  const int t = blockIdx.x, dir = blockIdx.y;
  const int tid = threadIdx.x;
  const float* W_ih = dir ? W_ih_b : W_ih_f;
  const float* bb   = dir ? b_b    : b_f;
  const float* aW   = dir ? aW_ih_b : aW_ih_f;
  const float* ab   = dir ? ab_b   : ab_f;
  const int src = dir ? (TSEQ - 1 - t) : t;

  __shared__ float xr[DEMB];
  if (tid < DEMB) xr[tid] = E[(size_t)inputs[src] * DEMB + tid];
  __syncthreads();

  float a0 = bb[tid], a1 = bb[H + tid], a2 = bb[2 * H + tid], a3 = ab[tid];
  for (int r = 0; r < DEMB; r += 4) {
    const float4 e4 = *reinterpret_cast<const float4*>(&xr[r]);
    const float ev[4] = {e4.x, e4.y, e4.z, e4.w};
#pragma unroll
    for (int kk = 0; kk < 4; ++kk) {
      const float* wp = W_ih + (size_t)(r + kk) * H3 + tid;
      a0 += ev[kk] * wp[0];
      a1 += ev[kk] * wp[H];
      a2 += ev[kk] * wp[2 * H];
      a3 += ev[kk] * aW[(size_t)(r + kk) * H + tid];
    }
  }
  float* xgrow = xg + ((size_t)dir * TSEQ + t) * H3;
  xgrow[tid]         = a0;
  xgrow[H + tid]     = a1;
  xgrow[2 * H + tid] = a2;
  xa[((size_t)dir * TSEQ + t) * H + tid] = a3;
}

// ---------------- K2: word-gate preacts (valid slots only), bf16 out --------
__global__ __launch_bounds__(256) void k_wordgates(
    const int* __restrict__ fw_ids, const int* __restrict__ fw_mask,
    const int* __restrict__ bw_ids, const int* __restrict__ bw_mask,
    const float* __restrict__ word_table,
    const float* __restrict__ wW_ih_f, const float* __restrict__ wb_f,
    const float* __restrict__ wW_ih_b, const float* __restrict__ wb_b,
    __hip_bfloat16* __restrict__ wg)
{
  const int t = blockIdx.x, dir = blockIdx.y;
  const int tid = threadIdx.x;
  const int* ids = (dir ? bw_ids : fw_ids) + t * KEND;
  const int* msk = (dir ? bw_mask : fw_mask) + t * KEND;
  const float* wW = dir ? wW_ih_b : wW_ih_f;
  const float* wb = dir ? wb_b    : wb_f;

  __shared__ float we[KEND][WD];
  for (int w = 0; w < KEND; ++w) {
    if (msk[w]) {
      const float* src = word_table + (size_t)ids[w] * WD;
      for (int i = tid; i < WD; i += 256) we[w][i] = src[i];
    }
  }
  __syncthreads();

  __hip_bfloat16* out = wg + ((size_t)dir * TSEQ + t) * KEND * H3;
  for (int w = 0; w < KEND; ++w) {
    if (!msk[w]) continue;
    float a0 = wb[tid], a1 = wb[H + tid], a2 = wb[2 * H + tid];
    for (int r = 0; r < WD; r += 4) {
      const float4 e4 = *reinterpret_cast<const float4*>(&we[w][r]);
      const float ev[4] = {e4.x, e4.y, e4.z, e4.w};
#pragma unroll
      for (int kk = 0; kk < 4; ++kk) {
        const float* wp = wW + (size_t)(r + kk) * H3 + tid;
        a0 += ev[kk] * wp[0];
        a1 += ev[kk] * wp[H];
        a2 += ev[kk] * wp[2 * H];
      }
    }
    out[w * H3 + tid]         = __float2bfloat16(a0);
    out[w * H3 + H + tid]     = __float2bfloat16(a1);
    out[w * H3 + 2 * H + tid] = __float2bfloat16(a2);
  }
}

// ---------------- K3: sequential lattice scan, 1 block per direction --------
__global__ __launch_bounds__(768) void k_scan(
    const float* __restrict__ xg, const float* __restrict__ xa,
    const __hip_bfloat16* __restrict__ wg, float* __restrict__ hseq,
    const int* __restrict__ fw_start, const int* __restrict__ fw_mask,
    const int* __restrict__ bw_start, const int* __restrict__ bw_mask,
    const float* __restrict__ W_hh_f, const float* __restrict__ aW_hh_f, const float* __restrict__ wW_hh_f,
    const float* __restrict__ W_hh_b, const float* __restrict__ aW_hh_b, const float* __restrict__ wW_hh_b)
{
  const int dir = blockIdx.x;
  const int tid = threadIdx.x;
  const int* startA = dir ? bw_start : fw_start;
  const int* maskA  = dir ? bw_mask  : fw_mask;
  const float* W_hh  = dir ? W_hh_b  : W_hh_f;
  const float* aW_hh = dir ? aW_hh_b : aW_hh_f;
  const float* wW_hh = dir ? wW_hh_b : wW_hh_f;

  // word start >= t-6 always (len in [2,7]) -> 8-deep ring is sufficient.
  __shared__ float ringH[8][H];
  __shared__ float ringC[8][H];
  __shared__ float pre[H3];        // char-gate preacts (i|o|g)
  __shared__ float pw[KEND][H3];   // word-gate preacts (wi|wf|wg)
  __shared__ float cwS[KEND][H];   // word cell outputs
  __shared__ float awS[KEND][H];   // alpha preacts
  __shared__ int stS[KEND], mkS[KEND], anyw;

  for (int i = tid; i < 8 * H; i += 768) {
    ringH[i >> 8][i & (H - 1)] = 0.f;
    ringC[i >> 8][i & (H - 1)] = 0.f;
  }
  __syncthreads();

  const int rg = tid & 3;       // 4-way k-split (reduced via shfl_xor)
  const int cg = tid >> 2;      // 192 column-quads of 4 cols
  const int j0 = cg * 4;
  const int k0 = rg * 64;

  for (int t = 0; t < TSEQ; ++t) {
    if (tid < KEND) { stS[tid] = startA[t * KEND + tid]; mkS[tid] = maskA[t * KEND + tid]; }
    __syncthreads();
    if (tid == 0)
      anyw = mkS[0] | mkS[1] | mkS[2] | mkS[3] | mkS[4] | mkS[5] | mkS[6] | mkS[7];

    const float* xgrow = xg + ((size_t)dir * TSEQ + t) * H3;
    const __hip_bfloat16* wgrow = wg + ((size_t)dir * TSEQ + t) * KEND * H3;

    // ---- phase 1: pre = xg + h@W_hh ; pw[w] = wg + H[start_w]@wW_hh
    // 9 matvec instances share one streamed read of W_hh/wW_hh columns.
#pragma unroll 1
    for (int p = 0; p < 3; ++p) {   // instance quads: {h,w0..2},{w3..6},{w7}
      bool act[4]; const float* vecs[4]; int widx[4];
      bool anyAct = false, anyWord = false;
#pragma unroll
      for (int i = 0; i < 4; ++i) {
        const int q = p * 4 + i;
        if (q == 0)           { act[i] = true;            vecs[i] = ringH[(t - 1) & 7]; widx[i] = -1; }
        else if (q <= KEND)   { const int w = q - 1;
                                act[i] = (mkS[w] != 0);   vecs[i] = ringH[stS[w] & 7];  widx[i] = w;
                                anyWord |= act[i]; }
        else                  { act[i] = false;           vecs[i] = ringH[0];           widx[i] = -1; }
        anyAct |= act[i];
      }
      if (!anyAct) continue;
      const bool needH = (p == 0);

      float acc[4][4] = {{0,0,0,0},{0,0,0,0},{0,0,0,0},{0,0,0,0}};
      for (int kq = 0; kq < 64; kq += 4) {
        const int k = k0 + kq;
        float4 v[4];
#pragma unroll
        for (int i = 0; i < 4; ++i)
          if (act[i]) v[i] = *reinterpret_cast<const float4*>(&vecs[i][k]);
#pragma unroll
        for (int kk = 0; kk < 4; ++kk) {
          float4 wh = {0,0,0,0}, ww = {0,0,0,0};
          if (needH)   wh = *reinterpret_cast<const float4*>(&W_hh[(size_t)(k + kk) * H3 + j0]);
          if (anyWord) ww = *reinterpret_cast<const float4*>(&wW_hh[(size_t)(k + kk) * H3 + j0]);
#pragma unroll
          for (int i = 0; i < 4; ++i) {
            if (!act[i]) continue;
            const float4 wv = (needH && i == 0) ? wh : ww;
            const float vk = (kk == 0) ? v[i].x : (kk == 1) ? v[i].y : (kk == 2) ? v[i].z : v[i].w;
            acc[i][0] += vk * wv.x;
            acc[i][1] += vk * wv.y;
            acc[i][2] += vk * wv.z;
            acc[i][3] += vk * wv.w;
          }
        }
      }
#pragma unroll
      for (int i = 0; i < 4; ++i) {
        if (!act[i]) continue;
#pragma unroll
        for (int c2 = 0; c2 < 4; ++c2) {
          float s = acc[i][c2];
          s += __shfl_xor(s, 1);
          s += __shfl_xor(s, 2);
          if (rg == 0) {
            const int j = j0 + c2;
            if (needH && i == 0) pre[j] = xgrow[j] + s;
            else {
              const int w = widx[i];
              pw[w][j] = __bfloat162float(wgrow[w * H3 + j]) + s;
            }
          }
        }
      }
    }
    __syncthreads();

    // ---- phase 2: word cells cw = sig(wf)*c_start + sig(wi)*tanh(wg)
    if (anyw && tid < H) {
#pragma unroll 1
      for (int w = 0; w < KEND; ++w) {
        if (!mkS[w]) continue;
        const float wi  = pw[w][tid];
        const float wf  = pw[w][H + tid];
        const float wgg = pw[w][2 * H + tid];
        const float cs  = ringC[stS[w] & 7][tid];
        cwS[w][tid] = sigf(wf) * cs + sigf(wi) * tanhf(wgg);
      }
    }
    __syncthreads();

    // ---- phase 3: alpha preacts aw[w] = xa + cw[w]@aW_hh (shared aW loads)
    if (anyw && tid < H) {
      const int rg2 = tid & 3;
      const int jb  = (tid >> 2) * 4;
      const int kb  = rg2 * 64;
      bool mb[KEND];
#pragma unroll
      for (int w = 0; w < KEND; ++w) mb[w] = (mkS[w] != 0);

      float acc[KEND][4];
#pragma unroll
      for (int w = 0; w < KEND; ++w)
#pragma unroll
        for (int c2 = 0; c2 < 4; ++c2) acc[w][c2] = 0.f;

      for (int kq = 0; kq < 64; kq += 4) {
        const int k = kb + kq;
        float4 cv[KEND];
#pragma unroll
        for (int w = 0; w < KEND; ++w)
          if (mb[w]) cv[w] = *reinterpret_cast<const float4*>(&cwS[w][k]);
#pragma unroll
        for (int kk = 0; kk < 4; ++kk) {
          const float4 av = *reinterpret_cast<const float4*>(&aW_hh[(size_t)(k + kk) * H + jb]);
#pragma unroll
          for (int w = 0; w < KEND; ++w) {
            if (!mb[w]) continue;
            const float ck = (kk == 0) ? cv[w].x : (kk == 1) ? cv[w].y : (kk == 2) ? cv[w].z : cv[w].w;
            acc[w][0] += ck * av.x;
            acc[w][1] += ck * av.y;
            acc[w][2] += ck * av.z;
            acc[w][3] += ck * av.w;
          }
        }
      }
      const float* xarow = xa + ((size_t)dir * TSEQ + t) * H;
#pragma unroll
      for (int w = 0; w < KEND; ++w) {
        if (!mb[w]) continue;
#pragma unroll
        for (int c2 = 0; c2 < 4; ++c2) {
          float s = acc[w][c2];
          s += __shfl_xor(s, 1);
          s += __shfl_xor(s, 2);
          if (rg2 == 0) awS[w][jb + c2] = xarow[jb + c2] + s;
        }
      }
    }
    __syncthreads();

    // ---- phase 4: merge + state update
    if (tid < H) {
      const int j = tid;
      const float i_s = sigf(pre[j]);
      const float o_s = sigf(pre[H + j]);
      const float g_t = tanhf(pre[2 * H + j]);
      float cnew;
      if (anyw) {
        const float e_i = expf(i_s);
        float num = e_i * g_t;
        float den = e_i;
#pragma unroll 1
        for (int w = 0; w < KEND; ++w) {
          if (!mkS[w]) continue;
          const float a  = sigf(awS[w][j]);
          const float ea = expf(a);
          num += ea * cwS[w][j];
          den += ea;
        }
        cnew = num / den;
      } else {
        const float cp = ringC[(t - 1) & 7][j];
        cnew = (1.f - i_s) * cp + i_s * g_t;
      }
      const float hnew = o_s * tanhf(cnew);
      ringH[t & 7][j] = hnew;
      ringC[t & 7][j] = cnew;
      hseq[((size_t)dir * TSEQ + t) * H + j] = hnew;
    }
    __syncthreads();
  }
}

// ---------------- K4: output projection -------------------------------------
__global__ __launch_bounds__(64) void k_proj(
    const float* __restrict__ hseq, const float* __restrict__ W_lin,
    const float* __restrict__ b_lin, float* __restrict__ out)
{
  const int t = blockIdx.x;
  const int tid = threadIdx.x;
  __shared__ float hrow[2 * H];
  for (int i = tid; i < H; i += 64) {
    hrow[i]     = hseq[(size_t)t * H + i];                          // fw
    hrow[H + i] = hseq[((size_t)TSEQ + (TSEQ - 1 - t)) * H + i];    // bw, re-flipped
  }
  __syncthreads();
  if (tid < CCLS) {
    float acc = b_lin[tid];
    for (int j = 0; j < 2 * H; ++j) acc += hrow[j] * W_lin[(size_t)j * CCLS + tid];
    out[(size_t)t * CCLS + tid] = acc;
  }
}

// ---------------------------------------------------------------------------
extern "C" void kernel_launch(void* const* d_in, const int* in_sizes, int n_in,
                              void* d_out, int out_size, void* d_ws, size_t ws_size,
                              hipStream_t stream)
{
  const int* inputs   = (const int*)d_in[0];
  const int* fw_ids   = (const int*)d_in[1];
  const int* fw_start = (const int*)d_in[2];
  const int* fw_mask  = (const int*)d_in[3];
  const int* bw_ids   = (const int*)d_in[4];
  const int* bw_start = (const int*)d_in[5];
  const int* bw_mask  = (const int*)d_in[6];
  // d_in[7] = length (2048), compile-time constant here
  const float* E          = (const float*)d_in[8];
  const float* word_table = (const float*)d_in[9];
  const float* W_lin      = (const float*)d_in[10];
  const float* b_lin      = (const float*)d_in[11];
  const float* fw_W_ih  = (const float*)d_in[12];
  const float* fw_W_hh  = (const float*)d_in[13];
  const float* fw_b     = (const float*)d_in[14];
  const float* fw_aW_ih = (const float*)d_in[15];
  const float* fw_aW_hh = (const float*)d_in[16];
  const float* fw_ab    = (const float*)d_in[17];
  const float* fw_wW_ih = (const float*)d_in[18];
  const float* fw_wW_hh = (const float*)d_in[19];
  const float* fw_wb    = (const float*)d_in[20];
  const float* bw_W_ih  = (const float*)d_in[21];
  const float* bw_W_hh  = (const float*)d_in[22];
  const float* bw_b     = (const float*)d_in[23];
  const float* bw_aW_ih = (const float*)d_in[24];
  const float* bw_aW_hh = (const float*)d_in[25];
  const float* bw_ab    = (const float*)d_in[26];
  const float* bw_wW_ih = (const float*)d_in[27];
  const float* bw_wW_hh = (const float*)d_in[28];
  const float* bw_wb    = (const float*)d_in[29];

  // workspace layout (bytes): xg 12.6M | xa 4.2M | hseq 4.2M | wg(bf16) 50.3M  => ~71.3 MB
  float* xg   = (float*)d_ws;                               // 2*T*768 f32
  float* xa   = xg + (size_t)2 * TSEQ * H3;                 // 2*T*256 f32
  float* hseq = xa + (size_t)2 * TSEQ * H;                  // 2*T*256 f32
  __hip_bfloat16* wg = (__hip_bfloat16*)(hseq + (size_t)2 * TSEQ * H);  // 2*T*8*768 bf16

  k_embed<<<dim3(TSEQ, 2), 256, 0, stream>>>(
      inputs, E, fw_W_ih, fw_b, fw_aW_ih, fw_ab, bw_W_ih, bw_b, bw_aW_ih, bw_ab, xg, xa);
  k_wordgates<<<dim3(TSEQ, 2), 256, 0, stream>>>(
      fw_ids, fw_mask, bw_ids, bw_mask, word_table, fw_wW_ih, fw_wb, bw_wW_ih, bw_wb, wg);
  k_scan<<<2, 768, 0, stream>>>(
      xg, xa, wg, hseq, fw_start, fw_mask, bw_start, bw_mask,
      fw_W_hh, fw_aW_hh, fw_wW_hh, bw_W_hh, bw_aW_hh, bw_wW_hh);
  k_proj<<<TSEQ, 64, 0, stream>>>(hseq, W_lin, b_lin, (float*)d_out);
}

// Round 2
// 21504.700 us; speedup vs baseline: 7.6572x; 7.6572x over previous
//
#include <hip/hip_runtime.h>
#include <hip/hip_bf16.h>

// ---------------------------------------------------------------------------
// Lattice LSTM (bidirectional) — round 1: LDS-resident-weight multi-block scan.
//
//   k_embed     : xg = x@W_ih + b (bf16), xa = x@aW_ih + ab (f32)   [parallel]
//   k_wordgates : wg = word_emb@wW_ih + wb (bf16)                   [parallel]
//   k_scan      : persistent, 16 blocks (8 per direction). Each block holds a
//                 1/8 column-slice of W_hh/wW_hh and a 1/8 k-slice of aW_hh in
//                 LDS (bf16, loaded once). Per step: slice matvecs from local
//                 full (h,c) ring -> global exchange -> ONE device barrier ->
//                 redundant full merge in every block (keeps ring local).
//   k_proj      : out = concat(hf, hb_flipped) @ W_lin + b_lin.
// ---------------------------------------------------------------------------

#define TSEQ 2048
#define KEND 8
#define DEMB 100
#define H    256
#define H3   768
#define WD   300
#define CCLS 18

#define NBLK 8          // blocks per direction
#define ESL  32         // elems per block (H/NBLK)
#define NTH  512        // threads per scan block

// LDS region offsets (bytes) for k_scan
#define LOFF_WC    0        // 96 cols * 264 bf16 (chunk-XOR swizzled)  50688
#define LOFF_WW    50688    // same                                     50688
#define LOFF_WA    101376   // 256 cols * 40 bf16                       20480
#define LOFF_RH    121856   // ring H: 8 slots * 288 f32 (chunk-padded)  9216
#define LOFF_RC    131072   // ring C                                    9216
#define LOFF_PW    140288   // pwS[8][96] f32                            3072
#define LOFF_CW    143360   // cwOwn[8][32] f32                          1024
#define LOFF_META  144384   // ints
#define SMEM_SCAN  144576

__device__ __forceinline__ float sigf(float x) { return 1.0f / (1.0f + expf(-x)); }
__device__ __forceinline__ float blo(unsigned u) { return __uint_as_float(u << 16); }
__device__ __forceinline__ float bhi(unsigned u) { return __uint_as_float(u & 0xffff0000u); }
__device__ __forceinline__ int ridx(int j) { return (j >> 6) * 72 + (j & 63); }  // ring pad

// ---------------- K1: char embedding -> gate / alpha input preacts ----------
__global__ __launch_bounds__(256) void k_embed(
    const int* __restrict__ inputs, const float* __restrict__ E,
    const float* __restrict__ W_ih_f, const float* __restrict__ b_f,
    const float* __restrict__ aW_ih_f, const float* __restrict__ ab_f,
    const float* __restrict__ W_ih_b, const float* __restrict__ b_b,
    const float* __restrict__ aW_ih_b, const float* __restrict__ ab_b,
    __hip_bfloat16* __restrict__ xg, float* __restrict__ xa)
{
  const int t = blockIdx.x, dir = blockIdx.y;
  const int tid = threadIdx.x;
  const float* W_ih = dir ? W_ih_b : W_ih_f;
  const float* bb   = dir ? b_b    : b_f;
  const float* aW   = dir ? aW_ih_b : aW_ih_f;
  const float* ab   = dir ? ab_b   : ab_f;
  const int src = dir ? (TSEQ - 1 - t) : t;

  __shared__ float xr[DEMB];
  if (tid < DEMB) xr[tid] = E[(size_t)inputs[src] * DEMB + tid];
  __syncthreads();

  float a0 = bb[tid], a1 = bb[H + tid], a2 = bb[2 * H + tid], a3 = ab[tid];
  for (int r = 0; r < DEMB; r += 4) {
    const float4 e4 = *reinterpret_cast<const float4*>(&xr[r]);
    const float ev[4] = {e4.x, e4.y, e4.z, e4.w};
#pragma unroll
    for (int kk = 0; kk < 4; ++kk) {
      const float* wp = W_ih + (size_t)(r + kk) * H3 + tid;
      a0 += ev[kk] * wp[0];
      a1 += ev[kk] * wp[H];
      a2 += ev[kk] * wp[2 * H];
      a3 += ev[kk] * aW[(size_t)(r + kk) * H + tid];
    }
  }
  __hip_bfloat16* xgrow = xg + ((size_t)dir * TSEQ + t) * H3;
  xgrow[tid]         = __float2bfloat16(a0);
  xgrow[H + tid]     = __float2bfloat16(a1);
  xgrow[2 * H + tid] = __float2bfloat16(a2);
  xa[((size_t)dir * TSEQ + t) * H + tid] = a3;
}

// ---------------- K2: word-gate preacts (valid slots only), bf16 out --------
__global__ __launch_bounds__(256) void k_wordgates(
    const int* __restrict__ fw_ids, const int* __restrict__ fw_mask,
    const int* __restrict__ bw_ids, const int* __restrict__ bw_mask,
    const float* __restrict__ word_table,
    const float* __restrict__ wW_ih_f, const float* __restrict__ wb_f,
    const float* __restrict__ wW_ih_b, const float* __restrict__ wb_b,
    __hip_bfloat16* __restrict__ wg)
{
  const int t = blockIdx.x, dir = blockIdx.y;
  const int tid = threadIdx.x;
  const int* ids = (dir ? bw_ids : fw_ids) + t * KEND;
  const int* msk = (dir ? bw_mask : fw_mask) + t * KEND;
  const float* wW = dir ? wW_ih_b : wW_ih_f;
  const float* wb = dir ? wb_b    : wb_f;

  __shared__ float we[KEND][WD];
  for (int w = 0; w < KEND; ++w) {
    if (msk[w]) {
      const float* src = word_table + (size_t)ids[w] * WD;
      for (int i = tid; i < WD; i += 256) we[w][i] = src[i];
    }
  }
  __syncthreads();

  __hip_bfloat16* out = wg + ((size_t)dir * TSEQ + t) * KEND * H3;
  for (int w = 0; w < KEND; ++w) {
    if (!msk[w]) continue;
    float a0 = wb[tid], a1 = wb[H + tid], a2 = wb[2 * H + tid];
    for (int r = 0; r < WD; r += 4) {
      const float4 e4 = *reinterpret_cast<const float4*>(&we[w][r]);
      const float ev[4] = {e4.x, e4.y, e4.z, e4.w};
#pragma unroll
      for (int kk = 0; kk < 4; ++kk) {
        const float* wp = wW + (size_t)(r + kk) * H3 + tid;
        a0 += ev[kk] * wp[0];
        a1 += ev[kk] * wp[H];
        a2 += ev[kk] * wp[2 * H];
      }
    }
    out[w * H3 + tid]         = __float2bfloat16(a0);
    out[w * H3 + H + tid]     = __float2bfloat16(a1);
    out[w * H3 + 2 * H + tid] = __float2bfloat16(a2);
  }
}

// ---------------- K3: persistent lattice scan, 8 blocks per direction -------
__global__ __launch_bounds__(NTH, 1) void k_scan(
    const __hip_bfloat16* __restrict__ xg, const float* __restrict__ xa,
    const __hip_bfloat16* __restrict__ wg, float* __restrict__ hseq,
    const int* __restrict__ fw_start, const int* __restrict__ fw_mask,
    const int* __restrict__ bw_start, const int* __restrict__ bw_mask,
    const float* __restrict__ W_hh_f, const float* __restrict__ aW_hh_f, const float* __restrict__ wW_hh_f,
    const float* __restrict__ W_hh_b, const float* __restrict__ aW_hh_b, const float* __restrict__ wW_hh_b,
    float* __restrict__ preX, float* __restrict__ cwX, float* __restrict__ aPX,
    unsigned* __restrict__ bar)
{
  extern __shared__ char smem[];
  __hip_bfloat16* Wc = (__hip_bfloat16*)(smem + LOFF_WC);
  __hip_bfloat16* Ww = (__hip_bfloat16*)(smem + LOFF_WW);
  __hip_bfloat16* Wa = (__hip_bfloat16*)(smem + LOFF_WA);
  float* ringH = (float*)(smem + LOFF_RH);
  float* ringC = (float*)(smem + LOFF_RC);
  float* pwS   = (float*)(smem + LOFF_PW);    // [8][96]
  float* cwOwn = (float*)(smem + LOFF_CW);    // [8][32]
  int*   meta  = (int*)(smem + LOFF_META);
  int* mkS = meta; int* stS = meta + 8; int* wSlot = meta + 16; int* wStart = meta + 24;
  // meta[32] = nw

  const int tid  = threadIdx.x;
  const int dir  = blockIdx.x >> 3;
  const int role = blockIdx.x & 7;
  const int e0   = role * ESL;

  const int* startA = dir ? bw_start : fw_start;
  const int* maskA  = dir ? bw_mask  : fw_mask;
  const float* W_hh  = dir ? W_hh_b  : W_hh_f;
  const float* aW_hh = dir ? aW_hh_b : aW_hh_f;
  const float* wW_hh = dir ? wW_hh_b : wW_hh_f;
  unsigned* ctr = bar + dir * 32;   // 128 B apart

  // ---- one-time: load weight slices into LDS (bf16, chunk-XOR swizzled) ----
  for (int f = tid; f < 96 * 256; f += NTH) {
    const int kc = f / 96, lc = f - kc * 96;
    const int g = lc >> 5, ce = lc & 31;
    const int gc = g * 256 + e0 + ce;
    const int ks = kc >> 6;
    const int sidx = (lc ^ ks) * 264 + ks * 64 + (kc & 63);
    Wc[sidx] = __float2bfloat16(W_hh[(size_t)kc * H3 + gc]);
    Ww[sidx] = __float2bfloat16(wW_hh[(size_t)kc * H3 + gc]);
  }
  for (int f = tid; f < 256 * 32; f += NTH) {
    const int j = f >> 5, kk = f & 31;
    Wa[j * 40 + kk] = __float2bfloat16(aW_hh[(size_t)(e0 + kk) * H + j]);
  }
  for (int i = tid; i < 8 * 288; i += NTH) { ringH[i] = 0.f; ringC[i] = 0.f; }
  __syncthreads();

  for (int t = 0; t < TSEQ; ++t) {
    const int par = t & 1;
    if (tid < KEND) {
      mkS[tid] = maskA[t * KEND + tid];
      stS[tid] = startA[t * KEND + tid];
    }
    __syncthreads();
    if (tid == 0) {
      int n = 0;
      for (int s = 0; s < KEND; ++s)
        if (mkS[s]) { wSlot[n] = s; wStart[n] = stS[s]; ++n; }
      meta[32] = n;
    }
    __syncthreads();
    const int nw = meta[32];

    float* preXg = preX + (dir * 2 + par) * H3;
    float* cwXg  = cwX + (size_t)(dir * 2 + par) * KEND * H;
    float* aPg   = aPX + (size_t)(((dir * 2 + par) * NBLK + role) * KEND) * H;
    const float* aPall = aPX + (size_t)((dir * 2 + par) * NBLK * KEND) * H;
    const __hip_bfloat16* xgrow  = xg + ((size_t)dir * TSEQ + t) * H3;
    const __hip_bfloat16* wgbase = wg + ((size_t)dir * TSEQ + t) * KEND * H3;
    const float* xaRow = xa + ((size_t)dir * TSEQ + t) * H;

    // ---- phase A: slice matvecs (char + word gates), from local ring -------
    const int totU = (1 + nw) * 96;
    for (int u = tid; u < totU; u += NTH) {
      const int inst = u / 96;
      const int r = u - inst * 96;
      const int cb = r >> 2, ks = r & 3;
      const int lc0 = cb * 4;
      const int hslot = (inst == 0) ? ((t - 1) & 7) : (wStart[inst - 1] & 7);
      const float* hv = ringH + hslot * 288 + ks * 72;
      const __hip_bfloat16* Wsel = (inst == 0) ? Wc : Ww;
      int wb0 = ((lc0 + 0) ^ ks) * 264 + ks * 64;
      int wb1 = ((lc0 + 1) ^ ks) * 264 + ks * 64;
      int wb2 = ((lc0 + 2) ^ ks) * 264 + ks * 64;
      int wb3 = ((lc0 + 3) ^ ks) * 264 + ks * 64;
      float acc0 = 0.f, acc1 = 0.f, acc2 = 0.f, acc3 = 0.f;
#pragma unroll
      for (int kk = 0; kk < 64; kk += 8) {
        const float4 h0 = *(const float4*)(hv + kk);
        const float4 h1 = *(const float4*)(hv + kk + 4);
        {
          const uint4 q = *(const uint4*)(Wsel + wb0 + kk);
          acc0 += h0.x * blo(q.x) + h0.y * bhi(q.x) + h0.z * blo(q.y) + h0.w * bhi(q.y)
                + h1.x * blo(q.z) + h1.y * bhi(q.z) + h1.z * blo(q.w) + h1.w * bhi(q.w);
        }
        {
          const uint4 q = *(const uint4*)(Wsel + wb1 + kk);
          acc1 += h0.x * blo(q.x) + h0.y * bhi(q.x) + h0.z * blo(q.y) + h0.w * bhi(q.y)
                + h1.x * blo(q.z) + h1.y * bhi(q.z) + h1.z * blo(q.w) + h1.w * bhi(q.w);
        }
        {
          const uint4 q = *(const uint4*)(Wsel + wb2 + kk);
          acc2 += h0.x * blo(q.x) + h0.y * bhi(q.x) + h0.z * blo(q.y) + h0.w * bhi(q.y)
                + h1.x * blo(q.z) + h1.y * bhi(q.z) + h1.z * blo(q.w) + h1.w * bhi(q.w);
        }
        {
          const uint4 q = *(const uint4*)(Wsel + wb3 + kk);
          acc3 += h0.x * blo(q.x) + h0.y * bhi(q.x) + h0.z * blo(q.y) + h0.w * bhi(q.y)
                + h1.x * blo(q.z) + h1.y * bhi(q.z) + h1.z * blo(q.w) + h1.w * bhi(q.w);
        }
      }
      acc0 += __shfl_xor(acc0, 1); acc0 += __shfl_xor(acc0, 2);
      acc1 += __shfl_xor(acc1, 1); acc1 += __shfl_xor(acc1, 2);
      acc2 += __shfl_xor(acc2, 1); acc2 += __shfl_xor(acc2, 2);
      acc3 += __shfl_xor(acc3, 1); acc3 += __shfl_xor(acc3, 2);
      if (ks == 0) {
        const int g = lc0 >> 5, ce0 = lc0 & 31;
        const int gc0 = g * 256 + e0 + ce0;
        if (inst == 0) {
          const ushort4 xv = *(const ushort4*)((const unsigned short*)xgrow + gc0);
          float4 st;
          st.x = blo((unsigned)xv.x << 0 | 0) + acc0;  // placeholder, fixed below
          st.x = __uint_as_float((unsigned)xv.x << 16) + acc0;
          st.y = __uint_as_float((unsigned)xv.y << 16) + acc1;
          st.z = __uint_as_float((unsigned)xv.z << 16) + acc2;
          st.w = __uint_as_float((unsigned)xv.w << 16) + acc3;
          *(float4*)(preXg + gc0) = st;
        } else {
          const int w = inst - 1;
          const __hip_bfloat16* wgrow = wgbase + (size_t)wSlot[w] * H3;
          const ushort4 wv = *(const ushort4*)((const unsigned short*)wgrow + gc0);
          pwS[w * 96 + lc0 + 0] = __uint_as_float((unsigned)wv.x << 16) + acc0;
          pwS[w * 96 + lc0 + 1] = __uint_as_float((unsigned)wv.y << 16) + acc1;
          pwS[w * 96 + lc0 + 2] = __uint_as_float((unsigned)wv.z << 16) + acc2;
          pwS[w * 96 + lc0 + 3] = __uint_as_float((unsigned)wv.w << 16) + acc3;
        }
      }
    }
    __syncthreads();

    if (nw > 0) {
      // ---- word cells for own elems --------------------------------------
      for (int u = tid; u < nw * ESL; u += NTH) {
        const int i = u >> 5, ce = u & 31;
        const int j = e0 + ce;
        const float wi  = pwS[i * 96 + ce];
        const float wf  = pwS[i * 96 + 32 + ce];
        const float wgg = pwS[i * 96 + 64 + ce];
        const float cs  = ringC[(wStart[i] & 7) * 288 + ridx(j)];
        const float cwv = sigf(wf) * cs + sigf(wi) * tanhf(wgg);
        cwOwn[i * ESL + ce] = cwv;
        cwXg[i * H + j] = cwv;
      }
      __syncthreads();
      // ---- alpha partials: own k-slice, all 256 j ------------------------
      for (int u = tid; u < nw * H; u += NTH) {
        const int i = u >> 8, j = u & 255;
        float s = 0.f;
#pragma unroll
        for (int kk = 0; kk < 32; kk += 8) {
          const float4 c0 = *(const float4*)(cwOwn + i * ESL + kk);
          const float4 c1 = *(const float4*)(cwOwn + i * ESL + kk + 4);
          const uint4 q = *(const uint4*)(Wa + j * 40 + kk);
          s += c0.x * blo(q.x) + c0.y * bhi(q.x) + c0.z * blo(q.y) + c0.w * bhi(q.y)
             + c1.x * blo(q.z) + c1.y * bhi(q.z) + c1.z * blo(q.w) + c1.w * bhi(q.w);
        }
        aPg[i * H + j] = s;
      }
    }

    // ---- device barrier (release own writes, acquire others') -------------
    __threadfence();
    __syncthreads();
    if (tid == 0) {
      __hip_atomic_fetch_add(ctr, 1u, __ATOMIC_RELAXED, __HIP_MEMORY_SCOPE_AGENT);
      const unsigned target = (unsigned)(t + 1) * NBLK;
      while (__hip_atomic_load(ctr, __ATOMIC_RELAXED, __HIP_MEMORY_SCOPE_AGENT) < target)
        __builtin_amdgcn_s_sleep(1);
      __threadfence();
    }
    __syncthreads();

    // ---- phase B: redundant full merge (keeps ring local) ------------------
    if (tid < H) {
      const int j = tid;
      const float i_s = sigf(preXg[j]);
      const float o_s = sigf(preXg[H + j]);
      const float g_t = tanhf(preXg[2 * H + j]);
      float cnew;
      if (nw > 0) {
        const float e_i = expf(i_s);
        float num = e_i * g_t, den = e_i;
        const float xav = xaRow[j];
        for (int i = 0; i < nw; ++i) {
          float ap = xav;
#pragma unroll
          for (int b = 0; b < NBLK; ++b) ap += aPall[(b * KEND + i) * H + j];
          const float a  = sigf(ap);
          const float ea = expf(a);
          num += ea * cwXg[i * H + j];
          den += ea;
        }
        cnew = num / den;
      } else {
        const float cp = ringC[((t - 1) & 7) * 288 + ridx(j)];
        cnew = (1.f - i_s) * cp + i_s * g_t;
      }
      const float hnew = o_s * tanhf(cnew);
      const int ro = ridx(j);
      ringH[(t & 7) * 288 + ro] = hnew;
      ringC[(t & 7) * 288 + ro] = cnew;
      if ((j >> 5) == role) hseq[((size_t)dir * TSEQ + t) * H + j] = hnew;
    }
    __syncthreads();
  }
}

// ---------------- K4: output projection -------------------------------------
__global__ __launch_bounds__(64) void k_proj(
    const float* __restrict__ hseq, const float* __restrict__ W_lin,
    const float* __restrict__ b_lin, float* __restrict__ out)
{
  const int t = blockIdx.x;
  const int tid = threadIdx.x;
  __shared__ float hrow[2 * H];
  for (int i = tid; i < H; i += 64) {
    hrow[i]     = hseq[(size_t)t * H + i];
    hrow[H + i] = hseq[((size_t)TSEQ + (TSEQ - 1 - t)) * H + i];
  }
  __syncthreads();
  if (tid < CCLS) {
    float acc = b_lin[tid];
    for (int j = 0; j < 2 * H; ++j) acc += hrow[j] * W_lin[(size_t)j * CCLS + tid];
    out[(size_t)t * CCLS + tid] = acc;
  }
}

// ---------------------------------------------------------------------------
extern "C" void kernel_launch(void* const* d_in, const int* in_sizes, int n_in,
                              void* d_out, int out_size, void* d_ws, size_t ws_size,
                              hipStream_t stream)
{
  const int* inputs   = (const int*)d_in[0];
  const int* fw_ids   = (const int*)d_in[1];
  const int* fw_start = (const int*)d_in[2];
  const int* fw_mask  = (const int*)d_in[3];
  const int* bw_ids   = (const int*)d_in[4];
  const int* bw_start = (const int*)d_in[5];
  const int* bw_mask  = (const int*)d_in[6];
  const float* E          = (const float*)d_in[8];
  const float* word_table = (const float*)d_in[9];
  const float* W_lin      = (const float*)d_in[10];
  const float* b_lin      = (const float*)d_in[11];
  const float* fw_W_ih  = (const float*)d_in[12];
  const float* fw_W_hh  = (const float*)d_in[13];
  const float* fw_b     = (const float*)d_in[14];
  const float* fw_aW_ih = (const float*)d_in[15];
  const float* fw_aW_hh = (const float*)d_in[16];
  const float* fw_ab    = (const float*)d_in[17];
  const float* fw_wW_ih = (const float*)d_in[18];
  const float* fw_wW_hh = (const float*)d_in[19];
  const float* fw_wb    = (const float*)d_in[20];
  const float* bw_W_ih  = (const float*)d_in[21];
  const float* bw_W_hh  = (const float*)d_in[22];
  const float* bw_b     = (const float*)d_in[23];
  const float* bw_aW_ih = (const float*)d_in[24];
  const float* bw_aW_hh = (const float*)d_in[25];
  const float* bw_ab    = (const float*)d_in[26];
  const float* bw_wW_ih = (const float*)d_in[27];
  const float* bw_wW_hh = (const float*)d_in[28];
  const float* bw_wb    = (const float*)d_in[29];

  char* p = (char*)d_ws;
  __hip_bfloat16* xg = (__hip_bfloat16*)p;  p += (size_t)2 * TSEQ * H3 * 2;       // 6.3 MB
  float* xa   = (float*)p;                  p += (size_t)2 * TSEQ * H * 4;        // 4.2 MB
  float* hseq = (float*)p;                  p += (size_t)2 * TSEQ * H * 4;        // 4.2 MB
  __hip_bfloat16* wg = (__hip_bfloat16*)p;  p += (size_t)2 * TSEQ * KEND * H3 * 2; // 50.3 MB
  float* preX = (float*)p;                  p += (size_t)2 * 2 * H3 * 4;
  float* cwX  = (float*)p;                  p += (size_t)2 * 2 * KEND * H * 4;
  float* aPX  = (float*)p;                  p += (size_t)2 * 2 * NBLK * KEND * H * 4;
  unsigned* bar = (unsigned*)p;             p += 256;

  hipFuncSetAttribute((const void*)k_scan,
                      hipFuncAttributeMaxDynamicSharedMemorySize, SMEM_SCAN);
  hipMemsetAsync(bar, 0, 256, stream);

  k_embed<<<dim3(TSEQ, 2), 256, 0, stream>>>(
      inputs, E, fw_W_ih, fw_b, fw_aW_ih, fw_ab, bw_W_ih, bw_b, bw_aW_ih, bw_ab, xg, xa);
  k_wordgates<<<dim3(TSEQ, 2), 256, 0, stream>>>(
      fw_ids, fw_mask, bw_ids, bw_mask, word_table, fw_wW_ih, fw_wb, bw_wW_ih, bw_wb, wg);
  k_scan<<<16, NTH, SMEM_SCAN, stream>>>(
      xg, xa, wg, hseq, fw_start, fw_mask, bw_start, bw_mask,
      fw_W_hh, fw_aW_hh, fw_wW_hh, bw_W_hh, bw_aW_hh, bw_wW_hh,
      preX, cwX, aPX, bar);
  k_proj<<<TSEQ, 64, 0, stream>>>(hseq, W_lin, b_lin, (float*)d_out);
}